// Round 1
// baseline (118.463 us; speedup 1.0000x reference)
//
#include <hip/hip_runtime.h>

#define SRC_LEN 256
#define TRG_LEN 256
#define BATCH   32
#define HID     512
#define ATT     128
#define CSCALE  2.885390081777927f   // 2*log2(e): exp2(CSCALE*x) == exp(2x)

typedef float  f32x4  __attribute__((ext_vector_type(4)));
typedef float  f32x2  __attribute__((ext_vector_type(2)));
typedef short  bf16x8 __attribute__((ext_vector_type(8)));

// manual RNE fp32->bf16 (inputs are finite normals; NaN path not needed)
__device__ inline unsigned short bfr(float x) {
    unsigned u = __builtin_bit_cast(unsigned, x);
    return (unsigned short)((u + 0x7fffu + ((u >> 16) & 1u)) >> 16);
}
__device__ inline unsigned pk2(float a, float b) {
    return (unsigned)bfr(a) | ((unsigned)bfr(b) << 16);
}

// ---------------------------------------------------------------------------
// MFMA projection v6: 32-row tiles, 512 blocks x 512 threads -> 2 blocks/CU.
// Rationale: v5's within-block wave doubling (1->2 waves/SIMD) did NOT move
// the total (115.9 -> 116.5): all 8 waves share one __syncthreads, so they
// stall in lockstep on the same vmcnt drain before the LDS stores each chunk.
// Two INDEPENDENT blocks per CU have uncorrelated barriers -> one block's
// compute hides the other's staging stall. LDS/block 48->40 KB, acc 4->2
// frags, same validated swizzle + staging coalescing.
// Wave w: m-rows (w&1)*16, n-cols (w>>1)*32 (1x2 mfma tiles, 2 acc).
// ---------------------------------------------------------------------------
__global__ __launch_bounds__(512, 4) void proj_mfma(
    const float* __restrict__ dec_out, const float* __restrict__ enc_outs,
    const float* __restrict__ W_s, const float* __restrict__ W_t,
    const float* __restrict__ b_t,
    float* __restrict__ encE, float* __restrict__ decD)
{
    __shared__ __align__(16) char smem[40960];
    char* aLb = smem;            // [2][32 rows][128 B] = 8 KB
    char* bLb = smem + 8192;     // [2][128 rows][128 B] = 32 KB

    const int tid   = threadIdx.x;
    const int blk   = blockIdx.x;
    const bool isDec = blk >= 256;
    const int blkL  = isDec ? blk - 256 : blk;
    const int bb    = blkL & 31;
    const int r0    = (blkL >> 5) * 32;   // s0 or t0
    const float* __restrict__ in = isDec ? dec_out : enc_outs;
    const float* __restrict__ W  = isDec ? W_t : W_s;

    const int lane   = tid & 63;
    const int w      = tid >> 6;        // 0..7
    const int woff_m = (w & 1) * 16;
    const int woff_n = (w >> 1) * 32;
    const int q      = lane >> 4;
    const int l15    = lane & 15;
    const int l7     = lane & 7;

    // staging: 512 threads; row srow = tid>>4 (0..31), float4 col skc = tid&15.
    // Consecutive tids -> consecutive 16B segments: fully coalesced.
    const int srow = tid >> 4;
    const int skc  = tid & 15;
    const int sg   = skc >> 1, shalf = skc & 1;
    const float* aGp = in + ((size_t)(r0 + srow) * BATCH + bb) * HID + skc * 4;
    const float* wGp = W + (size_t)srow * HID + skc * 4;

    float4 aR;      // A row srow
    float4 wR[4];   // W rows srow + it*32

    f32x4 acc[2];
    acc[0] = (f32x4)0.0f;
    acc[1] = (f32x4)0.0f;

    #define LOADG(c)                                                          \
        {                                                                     \
            aR = *(const float4*)(aGp + (size_t)(c) * 64);                    \
            _Pragma("unroll")                                                 \
            for (int it = 0; it < 4; ++it)                                    \
                wR[it] = *(const float4*)(wGp + (size_t)it * 32 * HID         \
                                          + (c) * 64);                        \
        }

    #define STORES(buf)                                                      \
        {                                                                    \
            char* ab = aLb + (buf) * 4096;                                   \
            {                                                                \
                const int i = srow;                                          \
                uint2 u;                                                     \
                u.x = pk2(aR.x, aR.y);                                       \
                u.y = pk2(aR.z, aR.w);                                       \
                *(uint2*)(ab + i * 128 + ((sg ^ (i & 7)) << 4)               \
                          + shalf * 8) = u;                                  \
            }                                                                \
            char* bp = bLb + (buf) * 16384;                                  \
            _Pragma("unroll")                                                \
            for (int it = 0; it < 4; ++it) {                                 \
                const int rw = srow + it * 32;                               \
                uint2 u;                                                     \
                u.x = pk2(wR[it].x, wR[it].y);                               \
                u.y = pk2(wR[it].z, wR[it].w);                               \
                *(uint2*)(bp + rw * 128 + ((sg ^ (rw & 7)) << 4)             \
                          + shalf * 8) = u;                                  \
            }                                                                \
        }

    LOADG(0);
    STORES(0);
    __syncthreads();

    for (int c = 0; c < 8; ++c) {
        if (c < 7) LOADG(c + 1);
        const char* ab = aLb + (c & 1) * 4096;
        const char* bp = bLb + (c & 1) * 16384;
        #pragma unroll
        for (int s = 0; s < 2; ++s) {
            const int sw = ((s * 4 + q) ^ l7) * 16;
            bf16x8 af = *(const bf16x8*)(ab + (woff_m + l15) * 128 + sw);
            bf16x8 bfv[2];
            #pragma unroll
            for (int ni = 0; ni < 2; ++ni)
                bfv[ni] = *(const bf16x8*)(bp + (woff_n + ni * 16 + l15) * 128 + sw);
            #pragma unroll
            for (int ni = 0; ni < 2; ++ni)
                acc[ni] = __builtin_amdgcn_mfma_f32_16x16x32_bf16(
                    af, bfv[ni], acc[ni], 0, 0, 0);
        }
        if (c < 7) STORES((c + 1) & 1);
        __syncthreads();
    }

    if (!isDec) {
        // E' = exp(-2*enc_att) -> LDS transpose (stride 132, float4-aligned)
        // -> [b][a>>2][s][4] store: one coalesced float4 per lane.
        float* T = (float*)smem;
        #pragma unroll
        for (int ni = 0; ni < 2; ++ni)
            #pragma unroll
            for (int r = 0; r < 4; ++r) {
                const int ml = woff_m + q * 4 + r;          // 0..31 (s-local)
                const int nl = woff_n + ni * 16 + l15;      // 0..127 (a)
                T[ml * 132 + nl] = __builtin_amdgcn_exp2f(-CSCALE * acc[ni][r]);
            }
        __syncthreads();
        {
            const int m  = tid & 31;     // s-local
            const int g0 = tid >> 5;     // 0..15
            #pragma unroll
            for (int p = 0; p < 2; ++p) {
                const int gq = g0 + p * 16;          // a-quad 0..31
                float4 v = *(const float4*)(T + m * 132 + gq * 4);
                *(float4*)(encE + (((size_t)bb * 32 + gq) * SRC_LEN + r0 + m) * 4) = v;
            }
        }
    } else {
        // D = exp(+2*(dec_att + b_t)), natural [t][b][a] store
        float bt[2];
        bt[0] = b_t[woff_n + l15];
        bt[1] = b_t[woff_n + 16 + l15];
        #pragma unroll
        for (int ni = 0; ni < 2; ++ni)
            #pragma unroll
            for (int r = 0; r < 4; ++r) {
                const int ml = woff_m + q * 4 + r;
                const int nl = woff_n + ni * 16 + l15;
                decD[((size_t)(r0 + ml) * BATCH + bb) * ATT + nl] =
                    __builtin_amdgcn_exp2f(CSCALE * (acc[ni][r] + bt[ni]));
            }
    }
    #undef LOADG
    #undef STORES
}

// ---------------------------------------------------------------------------
// Score v7: packed-FP32 (v_pk_*) over t-PAIRS. Score is issue-bound (HBM
// bytes = compulsory 27 MB, occupancy already 8 blocks/CU, VGPR=32), so the
// lever is instructions/element. The 4-term rational can't pack across a
// (cross-element x0*x1 products) but packs perfectly across two t's:
// x,a01,den,m01,m23,num,acc all become <2 x float>; E/n broadcast across the
// pair; only rcp stays scalar. decD is restaged in LDS interleaved as
// (d_tA[a], d_tB[a]) so packed operands come straight from ds_read, no movs.
// ~61 -> ~44 instr per g. Also: XCD-locality block swizzle (b = p&7 major)
// so each XCD's encE working set is 4 b-slices (512 KB << 4 MB L2).
// ---------------------------------------------------------------------------
__global__ __launch_bounds__(256) void score_kernel(
    const float* __restrict__ encE, const float* __restrict__ decD,
    const float* __restrict__ v_a, float* __restrict__ out)
{
    __shared__ __align__(16) float dPf[2][ATT][2];   // [pair][a][tA/tB]
    __shared__ float vS[ATT];
    __shared__ float sumvS;

    const int tid = threadIdx.x;
    // XCD swizzle: dispatch round-robins p%8 across XCDs; make b the p%8-major
    // digit so all 64 t-blocks of a b-group co-reside on one XCD's L2.
    const int p   = blockIdx.x;                 // 0..2047
    const int b   = (p & 7) * 4 + ((p >> 3) >> 6);
    const int t0  = ((p >> 3) & 63) * 4;

    if (tid < 64) {
        const int pr = tid >> 5, a4 = (tid & 31) * 4;
        const float4 dA = *(const float4*)(decD + ((size_t)(t0 + 2 * pr) * BATCH + b) * ATT + a4);
        const float4 dB = *(const float4*)(decD + ((size_t)(t0 + 2 * pr + 1) * BATCH + b) * ATT + a4);
        f32x2* dst = (f32x2*)&dPf[pr][a4][0];
        dst[0] = (f32x2){dA.x, dB.x};
        dst[1] = (f32x2){dA.y, dB.y};
        dst[2] = (f32x2){dA.z, dB.z};
        dst[3] = (f32x2){dA.w, dB.w};
    } else if (tid < 96) {
        const int l = tid - 64;
        *(float4*)(vS + l * 4) = *(const float4*)(v_a + l * 4);
    }
    __syncthreads();
    if (tid < 64) {
        float x = vS[tid] + vS[tid + 64];
        #pragma unroll
        for (int o = 32; o > 0; o >>= 1) x += __shfl_down(x, o);
        if (tid == 0) sumvS = x;
    }
    __syncthreads();

    f32x2 acc0 = {0.f, 0.f};
    f32x2 acc1 = {0.f, 0.f};
    const float* __restrict__ ep = encE + ((size_t)b * 32 * SRC_LEN + tid) * 4;

    #define PSTEP(ACC, PR)                                                 \
    {                                                                      \
        const f32x2* dp = (const f32x2*)&dPf[PR][g * 4][0];                \
        const f32x2 x0 = e0 + dp[0], x1 = e1 + dp[1];                      \
        const f32x2 x2 = e2 + dp[2], x3 = e3 + dp[3];                      \
        const f32x2 a01 = x0 * x1, a23 = x2 * x3;                          \
        const f32x2 den = a01 * a23;                                       \
        const f32x2 m01 = n0 * x1 + n1 * x0;                               \
        const f32x2 m23 = n2 * x3 + n3 * x2;                               \
        const f32x2 num = m01 * a23 + m23 * a01;                           \
        f32x2 r;                                                           \
        r[0] = __builtin_amdgcn_rcpf(den[0]);                              \
        r[1] = __builtin_amdgcn_rcpf(den[1]);                              \
        ACC += num * r;                                                    \
    }

    #pragma unroll
    for (int g = 0; g < 32; ++g) {
        const float4 E  = *(const float4*)(ep + (size_t)g * SRC_LEN * 4);
        const float4 vv = *(const float4*)(vS + g * 4);
        const f32x2 e0 = {E.x, E.x}, e1 = {E.y, E.y};
        const f32x2 e2 = {E.z, E.z}, e3 = {E.w, E.w};
        const f32x2 n0 = vv.x * e0, n1 = vv.y * e1;
        const f32x2 n2 = vv.z * e2, n3 = vv.w * e3;
        PSTEP(acc0, 0)
        PSTEP(acc1, 1)
    }
    #undef PSTEP

    const float sv = sumvS;
    out[((size_t)(t0 + 0) * BATCH + b) * SRC_LEN + tid] = sv - 2.0f * acc0[0];
    out[((size_t)(t0 + 1) * BATCH + b) * SRC_LEN + tid] = sv - 2.0f * acc0[1];
    out[((size_t)(t0 + 2) * BATCH + b) * SRC_LEN + tid] = sv - 2.0f * acc1[0];
    out[((size_t)(t0 + 3) * BATCH + b) * SRC_LEN + tid] = sv - 2.0f * acc1[1];
}

extern "C" void kernel_launch(void* const* d_in, const int* in_sizes, int n_in,
                              void* d_out, int out_size, void* d_ws, size_t ws_size,
                              hipStream_t stream) {
    const float* dec_out  = (const float*)d_in[0];
    const float* enc_outs = (const float*)d_in[1];
    const float* W_s      = (const float*)d_in[2];
    const float* W_t      = (const float*)d_in[3];
    const float* b_t      = (const float*)d_in[4];
    const float* v_a      = (const float*)d_in[5];
    float* out = (float*)d_out;

    float* encE = (float*)d_ws;                              // B*32*S*4 = 4 MB : exp(-2*enc_att), [b][a>>2][s][4]
    float* decD = encE + (size_t)BATCH * ATT * SRC_LEN;      // T*B*A    = 4 MB : exp(+2*dec_att), [t][b][a]

    proj_mfma<<<512, 512, 0, stream>>>(dec_out, enc_outs, W_s, W_t, b_t, encE, decD);

    score_kernel<<<2048, 256, 0, stream>>>(encE, decD, v_a, out);
}